// Round 3
// baseline (564.065 us; speedup 1.0000x reference)
//
#include <hip/hip_runtime.h>

using bf8 = __attribute__((ext_vector_type(8))) short;   // 8 bf16 (4 VGPRs) — MFMA A/B frag
using bf4 = __attribute__((ext_vector_type(4))) short;
using f4  = __attribute__((ext_vector_type(4))) float;   // MFMA C/D frag
using ui4 = __attribute__((ext_vector_type(4))) unsigned int;
using u32 = unsigned int;
using u16 = unsigned short;

#define NROWS 262144

// workspace layout (bytes)
#define FLAG_B 0                     // int: 0 = bf16 inputs, 1 = fp32 inputs
#define PU_B   128                   // [U1;U2] B-frags: 32768 u16 (64 frags)
#define PW2_B  (PU_B + 65536)        // [Whrz|Whn] B-frags: 49152 u16 (96 frags)
#define PE_B   (PW2_B + 98304)       // extension B-frags (x/bias fold): 16384 u16 (32 frags)
#define PACK_ITEMS 98304             // 32768 + 49152 + 16384

static __device__ __forceinline__ float bf2f(u16 u) {
    unsigned v = ((unsigned)u) << 16;
    return __builtin_bit_cast(float, v);
}
static __device__ __forceinline__ u16 f2bf(float f) {          // RNE
    unsigned x = __builtin_bit_cast(unsigned, f);
    x = x + 0x7fffu + ((x >> 16) & 1u);
    return (u16)(x >> 16);
}
static __device__ __forceinline__ u32 pk2t(float a, float b) { // truncate-pack 2 fp32 -> 2 bf16
    u32 ab = __builtin_bit_cast(u32, a), bb = __builtin_bit_cast(u32, b);
    return (ab >> 16) | (bb & 0xffff0000u);
}

template<bool FP32>
static __device__ __forceinline__ u16 ldw(const void* p, int i) {   // -> bf16 bits (RNE)
    if constexpr (FP32) return f2bf(((const float*)p)[i]);
    else                return ((const u16*)p)[i];
}
template<bool FP32>
static __device__ __forceinline__ float ldf(const void* p, int i) { // -> float
    if constexpr (FP32) return ((const float*)p)[i];
    else                return bf2f(((const u16*)p)[i]);
}
// 8 contiguous elements -> bf16 A-frag (fp32 path: truncation, 1 op/el)
template<bool FP32>
static __device__ __forceinline__ bf8 ld8(const void* base, int idx) {
    if constexpr (!FP32) {
        return *(const bf8*)((const u16*)base + idx);
    } else {
        const float* f = (const float*)base + idx;
        f4 u = *(const f4*)f;
        f4 v = *(const f4*)(f + 4);
        ui4 w;
        w[0] = pk2t(u[0], u[1]);
        w[1] = pk2t(u[2], u[3]);
        w[2] = pk2t(v[0], v[1]);
        w[3] = pk2t(v[2], v[3]);
        return __builtin_bit_cast(bf8, w);
    }
}

// mode detection: even-index u16 of bf16 N(0,1) never has exponent >= 0xC0;
// fp32 data's low mantissa halves hit it ~25%/sample. P(miss) = 0.75^256.
__global__ void detect_mode(const u16* __restrict__ h1u, int* __restrict__ flag) {
    if (threadIdx.x == 0 && blockIdx.x == 0) {
        int huge = 0;
#pragma unroll 8
        for (int i = 0; i < 256; ++i) {
            u16 v = h1u[i * 2];
            huge += (((v >> 7) & 0xFF) >= 0xC0);
        }
        *flag = (huge > 0) ? 1 : 0;
    }
}

// Pack weights into B-fragment order for mfma_f32_16x16x32_bf16:
// frag (nt,kb): lane l holds W[k = kb*32 + (l>>4)*8 + j][n = nt*16 + (l&15)], j=0..7
template<bool FP32>
__global__ void prep_pack(const void* __restrict__ U1, const void* __restrict__ U2,
                          const void* __restrict__ Whrz, const void* __restrict__ Whn,
                          const void* __restrict__ Wi, const void* __restrict__ bi,
                          const void* __restrict__ bhn, char* __restrict__ ws,
                          const int* __restrict__ flag)
{
    if ((*flag != 0) != FP32) return;
    int e = blockIdx.x * 256 + threadIdx.x;
    if (e >= PACK_ITEMS) return;
    u16* pU  = (u16*)(ws + PU_B);
    u16* pW2 = (u16*)(ws + PW2_B);
    u16* pE  = (u16*)(ws + PE_B);
    if (e < 32768) {                         // [U1;U2]: K=256 (KB=8), N=128 (NT=8)
        int j = e & 7, lane = (e >> 3) & 63, f = e >> 9;
        int kb = f & 7, nt = f >> 3;
        int k = kb * 32 + (lane >> 4) * 8 + j;
        int n = nt * 16 + (lane & 15);
        pU[e] = (k < 128) ? ldw<FP32>(U1, k * 128 + n) : ldw<FP32>(U2, (k - 128) * 128 + n);
    } else if (e < 81920) {                  // [Whrz|Whn]: K=128 (KB=4), N=384 (NT'=24)
        int e2 = e - 32768;
        int j = e2 & 7, lane = (e2 >> 3) & 63, f = e2 >> 9;
        int kb = f & 3, nt = f >> 2;
        int k = kb * 32 + (lane >> 4) * 8 + j;
        int n = nt * 16 + (lane & 15);
        pW2[e2] = (n < 256) ? ldw<FP32>(Whrz, k * 256 + n) : ldw<FP32>(Whn, k * 128 + (n - 256));
    } else {                                 // extension frags: K-block [x|1|0..], 4 sets x 8 nt
        int e3 = e - 81920;
        int j = e3 & 7, lane = (e3 >> 3) & 63, f = e3 >> 9;   // f in 0..31
        int nt = f & 7, set = f >> 3;        // set: 0=R 1=Z 2=N_h(bias only) 3=N_x
        int k = (lane >> 4) * 8 + j;         // k within the 32-wide extension block
        int n = nt * 16 + (lane & 15);       // gate-local col 0..127
        float v = 0.f;
        if (set == 0) {                      // SR += x@Wi_r + bi_r
            if (k < 4)       v = ldf<FP32>(Wi, k * 384 + n);
            else if (k == 4) v = ldf<FP32>(bi, n);
        } else if (set == 1) {               // SZ += x@Wi_z + bi_z
            if (k < 4)       v = ldf<FP32>(Wi, k * 384 + 128 + n);
            else if (k == 4) v = ldf<FP32>(bi, 128 + n);
        } else if (set == 2) {               // SN1 += bhn
            if (k == 4)      v = ldf<FP32>(bhn, n);
        } else {                             // SN2 = x@Wi_n + bi_n
            if (k < 4)       v = ldf<FP32>(Wi, k * 384 + 256 + n);
            else if (k == 4) v = ldf<FP32>(bi, 256 + n);
        }
        pE[e3] = f2bf(v);
    }
}

// Fused body: each wave independently owns 32 rows (two 16-row M-tiles sharing
// every B-frag). All LDS traffic is wave-private -> no __syncthreads.
template<bool FP32>
static __device__ __forceinline__ void gru_body(
    const void* __restrict__ xin, const void* __restrict__ h1,
    const void* __restrict__ h2, const char* __restrict__ ws,
    void* __restrict__ out, const int* __restrict__ flag, int write2)
{
    if ((*flag != 0) != FP32) return;
    // stride 136 el = 272 B rows: 16B-aligned for ds b128, breaks pow2 banks
    __shared__ __align__(16) u16 hl[4][32][136];
    const int tid = threadIdx.x;
    const int w  = tid >> 6;
    const int l  = tid & 63;
    const int q  = l >> 4;        // quad index
    const int lr = l & 15;        // A-frag row / C-frag col
    const int g0 = blockIdx.x * 128 + w * 32;

    const bf8* __restrict__ pU  = (const bf8*)(ws + PU_B);
    const bf8* __restrict__ pW2 = (const bf8*)(ws + PW2_B);
    const bf8* __restrict__ pE  = (const bf8*)(ws + PE_B);

    // ---------------- Phase A: h = [h1|h2] @ [U1;U2] ----------------
    bf8 a[2][8];
#pragma unroll
    for (int m = 0; m < 2; ++m) {
        int base = (g0 + m * 16 + lr) * 128 + q * 8;
#pragma unroll
        for (int kb = 0; kb < 4; ++kb) {
            a[m][kb]     = ld8<FP32>(h1, base + kb * 32);   // k in [0,128)   -> U1 rows
            a[m][kb + 4] = ld8<FP32>(h2, base + kb * 32);   // k in [128,256) -> U2 rows
        }
    }
#pragma unroll 1
    for (int nt = 0; nt < 8; ++nt) {
        f4 acc0 = {0.f, 0.f, 0.f, 0.f};
        f4 acc1 = {0.f, 0.f, 0.f, 0.f};
#pragma unroll
        for (int kb = 0; kb < 8; ++kb) {
            bf8 b = pU[(nt * 8 + kb) * 64 + l];
            acc0 = __builtin_amdgcn_mfma_f32_16x16x32_bf16(a[0][kb], b, acc0, 0, 0, 0);
            acc1 = __builtin_amdgcn_mfma_f32_16x16x32_bf16(a[1][kb], b, acc1, 0, 0, 0);
        }
        // C/D layout: col = lane&15, row = q*4 + reg  [m89-verified]
        int col = nt * 16 + lr;
#pragma unroll
        for (int i = 0; i < 4; ++i) {
            hl[w][q * 4 + i][col]      = f2bf(acc0[i]);     // RNE: h reused 3x
            hl[w][16 + q * 4 + i][col] = f2bf(acc1[i]);
        }
    }

    // ---------------- LDS round trip: h as A-operand ----------------
    bf8 ah[2][4];
#pragma unroll
    for (int m = 0; m < 2; ++m)
#pragma unroll
        for (int kb = 0; kb < 4; ++kb)
            ah[m][kb] = *(const bf8*)&hl[w][m * 16 + lr][kb * 32 + q * 8];

    // extension A-frag: [x0..x3, 1, 0, 0, 0] on q==0 lanes, zeros elsewhere
    bf8 ax[2];
#pragma unroll
    for (int m = 0; m < 2; ++m) {
        ui4 z = {0u, 0u, 0u, 0u};
        if (q == 0) {
            int row = g0 + m * 16 + lr;
            u16 xb[4];
            if constexpr (FP32) {
                f4 xv = *(const f4*)((const float*)xin + row * 4);
#pragma unroll
                for (int k = 0; k < 4; ++k) xb[k] = f2bf(xv[k]);
            } else {
                bf4 xv = *(const bf4*)((const u16*)xin + row * 4);
#pragma unroll
                for (int k = 0; k < 4; ++k) xb[k] = (u16)xv[k];
            }
            z[0] = (u32)xb[0] | ((u32)xb[1] << 16);
            z[1] = (u32)xb[2] | ((u32)xb[3] << 16);
            z[2] = 0x3f80u;                                  // bf16 1.0 at k==4
        }
        ax[m] = __builtin_bit_cast(bf8, z);
    }

    // ---------------- Phase C: gates + epilogue, per 16-col group ----------------
#pragma unroll 1
    for (int nt = 0; nt < 8; ++nt) {
        bf8 eR  = pE[(0 * 8 + nt) * 64 + l];
        bf8 eZ  = pE[(1 * 8 + nt) * 64 + l];
        bf8 eN1 = pE[(2 * 8 + nt) * 64 + l];
        bf8 eN2 = pE[(3 * 8 + nt) * 64 + l];
        f4 aR[2], aZ[2], aN1[2], aN2[2];
#pragma unroll
        for (int m = 0; m < 2; ++m) {
            aR[m]  = __builtin_amdgcn_mfma_f32_16x16x32_bf16(ax[m], eR,  (f4){0.f,0.f,0.f,0.f}, 0, 0, 0);
            aZ[m]  = __builtin_amdgcn_mfma_f32_16x16x32_bf16(ax[m], eZ,  (f4){0.f,0.f,0.f,0.f}, 0, 0, 0);
            aN1[m] = __builtin_amdgcn_mfma_f32_16x16x32_bf16(ax[m], eN1, (f4){0.f,0.f,0.f,0.f}, 0, 0, 0);
            aN2[m] = __builtin_amdgcn_mfma_f32_16x16x32_bf16(ax[m], eN2, (f4){0.f,0.f,0.f,0.f}, 0, 0, 0);
        }
#pragma unroll
        for (int kb = 0; kb < 4; ++kb) {
            bf8 bR = pW2[((nt     ) * 4 + kb) * 64 + l];   // Whr
            bf8 bZ = pW2[((nt + 8 ) * 4 + kb) * 64 + l];   // Whz
            bf8 bN = pW2[((nt + 16) * 4 + kb) * 64 + l];   // Whn
#pragma unroll
            for (int m = 0; m < 2; ++m) {
                aR[m]  = __builtin_amdgcn_mfma_f32_16x16x32_bf16(ah[m][kb], bR, aR[m],  0, 0, 0);
                aZ[m]  = __builtin_amdgcn_mfma_f32_16x16x32_bf16(ah[m][kb], bZ, aZ[m],  0, 0, 0);
                aN1[m] = __builtin_amdgcn_mfma_f32_16x16x32_bf16(ah[m][kb], bN, aN1[m], 0, 0, 0);
            }
        }
        int c = nt * 16 + lr;
#pragma unroll
        for (int m = 0; m < 2; ++m)
#pragma unroll
            for (int i = 0; i < 4; ++i) {
                int rl = m * 16 + q * 4 + i;
                float hv = bf2f(hl[w][rl][c]);
                // clamp-free: sigmoid/tanh saturate correctly at +-inf
                float r = __fdividef(1.f, 1.f + __expf(-aR[m][i]));
                float zg = __fdividef(1.f, 1.f + __expf(-aZ[m][i]));
                float t = aN2[m][i] + r * aN1[m][i];
                float n = 1.f - 2.f * __fdividef(1.f, __expf(2.f * t) + 1.f);
                float o = n + zg * (hv - n);
                if constexpr (FP32) {
                    int off = (g0 + rl) * 128 + c;
                    ((float*)out)[off] = o;
                    if (write2) ((float*)out)[NROWS * 128 + off] = o;
                } else {
                    hl[w][rl][c] = f2bf(o);
                }
            }
    }

    // ---------------- bf16 path: vectorized copy-out ----------------
    if constexpr (!FP32) {
        u16* o0 = (u16*)out;
#pragma unroll
        for (int ii = 0; ii < 8; ++ii) {
            int ch  = ii * 64 + l;
            int row = ch >> 4;
            int c8  = (ch & 15) * 8;
            bf8 v = *(const bf8*)&hl[w][row][c8];
            int off = (g0 + row) * 128 + c8;
            *(bf8*)(o0 + off) = v;
            if (write2) *(bf8*)(o0 + NROWS * 128 + off) = v;
        }
    }
}

// distinct names so rocprof identifies the live mode
__global__ __launch_bounds__(256, 4) void gru_b16(
    const void* x, const void* h1, const void* h2, const char* ws,
    void* out, const int* flag, int write2)
{ gru_body<false>(x, h1, h2, ws, out, flag, write2); }

__global__ __launch_bounds__(256, 4) void gru_f32(
    const void* x, const void* h1, const void* h2, const char* ws,
    void* out, const int* flag, int write2)
{ gru_body<true>(x, h1, h2, ws, out, flag, write2); }

extern "C" void kernel_launch(void* const* d_in, const int* in_sizes, int n_in,
                              void* d_out, int out_size, void* d_ws, size_t ws_size,
                              hipStream_t stream) {
    const void* x    = d_in[0];
    const void* h1   = d_in[1];
    const void* h2   = d_in[2];
    const void* U1   = d_in[3];
    const void* U2   = d_in[4];
    const void* Wi   = d_in[5];
    const void* bi   = d_in[6];
    const void* Whrz = d_in[7];
    const void* Whn  = d_in[8];
    const void* bhn  = d_in[9];
    char* ws   = (char*)d_ws;
    int* flag  = (int*)(ws + FLAG_B);
    int write2 = (out_size >= 2 * NROWS * 128) ? 1 : 0;

    detect_mode<<<1, 64, 0, stream>>>((const u16*)h1, flag);
    const int pblk = (PACK_ITEMS + 255) / 256;
    prep_pack<false><<<pblk, 256, 0, stream>>>(U1, U2, Whrz, Whn, Wi, bi, bhn, ws, flag);
    prep_pack<true ><<<pblk, 256, 0, stream>>>(U1, U2, Whrz, Whn, Wi, bi, bhn, ws, flag);
    gru_b16<<<NROWS / 128, 256, 0, stream>>>(x, h1, h2, ws, d_out, flag, write2);
    gru_f32<<<NROWS / 128, 256, 0, stream>>>(x, h1, h2, ws, d_out, flag, write2);
}